// Round 7
// baseline (255.983 us; speedup 1.0000x reference)
//
#include <hip/hip_runtime.h>
#include <hip/hip_bf16.h>
#include <stdint.h>

// ---------------------------------------------------------------------------
// MultiHeadSelfAttention: x[4,1024,1024] fp32 -> out[4,1024,1024] fp32
// R7: R6 with two fixes: (1) sA/sB LDS overlap in gemm_bt (sB now at +8192
// shorts); (2) Vt moved into the hb region (dead until FFN1) to keep ws
// footprint <= 74 MB. 6 dispatches.
// ---------------------------------------------------------------------------

#define B_ 4
#define S_ 1024
#define DM_ 1024
#define H_ 16
#define HD_ 64

typedef __attribute__((ext_vector_type(8))) short short8;
typedef __attribute__((ext_vector_type(4))) float f32x4;
typedef __attribute__((ext_vector_type(4))) unsigned short ushort4v;

#define GLB_AS(p) ((const __attribute__((address_space(1))) void*)(p))
#define LDS_AS(p) ((__attribute__((address_space(3))) void*)(p))

__device__ __forceinline__ void async_load16(const void* g, void* l) {
  __builtin_amdgcn_global_load_lds(GLB_AS(g), LDS_AS(l), 16, 0, 0);
}

__device__ __forceinline__ unsigned short f2bf(float x) {
  union { float f; unsigned int u; } v; v.f = x;
  unsigned int r = v.u + 0x7fffu + ((v.u >> 16) & 1u);  // RNE
  return (unsigned short)(r >> 16);
}

// 0.125 (1/sqrt(64)) * log2(e): folds softmax scale + exp->exp2 into Q proj.
#define QSCALE 0.18033688011112042f

// ---------------------------------------------------------------------------
// Fused prep: seg 0..5 fp32->bf16 convert; seg 6 mask pack; seg 7 bias concat
// ---------------------------------------------------------------------------
struct PrepArgs {
  const float* src[6];
  unsigned short* dst[6];
  int n4[6];
  const int* mask;
  unsigned long long* bits;
  unsigned int* rowflag;
  const float* bq;
  const float* bk;
  const float* bv;
  float* cb;
};

__global__ void prep_kernel(PrepArgs a) {
  const int seg = blockIdx.y;
  if (seg < 6) {
    const int n4 = a.n4[seg];
    const f32x4* __restrict__ src = (const f32x4*)a.src[seg];
    ushort4v* __restrict__ dst = (ushort4v*)a.dst[seg];
    for (int i = blockIdx.x * blockDim.x + threadIdx.x; i < n4;
         i += gridDim.x * blockDim.x) {
      f32x4 v = src[i];
      ushort4v o;
      o[0] = f2bf(v[0]); o[1] = f2bf(v[1]); o[2] = f2bf(v[2]); o[3] = f2bf(v[3]);
      dst[i] = o;
    }
  } else if (seg == 6) {
    // mask pack: 16 rows per block (4 waves x 4 rows)
    const int wave = threadIdx.x >> 6;
    const int lane = threadIdx.x & 63;
#pragma unroll
    for (int rr = 0; rr < 4; ++rr) {
      const int row = blockIdx.x * 16 + wave * 4 + rr;
      const int* mr = a.mask + (size_t)row * S_;
      unsigned long long allf = ~0ull;
#pragma unroll
      for (int g = 0; g < 16; ++g) {
        int mv = mr[g * 64 + lane];
        unsigned long long bal = __ballot(mv != 0);
        if (lane == g) a.bits[(size_t)row * 16 + g] = bal;
        allf &= bal;
      }
      if (lane == 0) a.rowflag[row] = (allf == ~0ull) ? 1u : 0u;
    }
  } else {
    const int i = blockIdx.x * 256 + threadIdx.x;
    if (i < 3072) {
      const float* src = (i < 1024) ? a.bq : (i < 2048) ? a.bk : a.bv;
      a.cb[i] = src[i & 1023];
    }
  }
}

// ---------------------------------------------------------------------------
// NT GEMM, BK=64, XOR chunk swizzle. EPI_QKV: Q/K token-major into Cqkv
// (Q pre-scaled); V blocks (n0>=2048) transposed in-epilogue -> Vt[bh][d][s].
// ---------------------------------------------------------------------------
enum { EPI_QKV = 0, EPI_RELU_BF16 = 2, EPI_F32 = 3, EPI_PARTIAL = 4 };

template <int EPI>
__global__ __launch_bounds__(256, 3) void gemm_bt(
    const unsigned short* __restrict__ A, const unsigned short* __restrict__ Bt,
    const float* __restrict__ bias, void* __restrict__ Cp,
    unsigned short* __restrict__ Vt, int M, int N, int K, int Kld) {
  // 34816 B. Main loop: sA = smem[0..8192), sB = smem[8192..16384) (shorts).
  // V-epilogue reuses the whole buffer (after barrier) as a 128x136 tile.
  __shared__ __align__(16) unsigned short smem[128 * 136];
  unsigned short* sA = smem;
  unsigned short* sB = smem + 128 * 64;  // FIX R6: was 128*32 (overlapped sA)

  const int tid = threadIdx.x;
  const int lane = tid & 63;
  const int wave = tid >> 6;
  const int quad = lane >> 4;
  const int l15 = lane & 15;
  const int swzb = l15 & 7;
  const int m0 = blockIdx.y * 128;
  const int n0 = blockIdx.x * 128;
  const int wm = (wave >> 1) * 64;
  const int wn = (wave & 1) * 64;
  const int kz = blockIdx.z * K;

  f32x4 acc[4][4];
#pragma unroll
  for (int i = 0; i < 4; ++i)
#pragma unroll
    for (int j = 0; j < 4; ++j) acc[i][j] = (f32x4){0.f, 0.f, 0.f, 0.f};

  const int srow = tid >> 3;
  const int scol = ((tid & 7) ^ (srow & 7)) * 8;
  const unsigned short* gA = A + (size_t)(m0 + srow) * Kld + kz + scol;
  const unsigned short* gB = Bt + (size_t)(n0 + srow) * Kld + kz + scol;
  unsigned short* lA = sA + tid * 8;
  unsigned short* lB = sB + tid * 8;

  for (int k0 = 0; k0 < K; k0 += 64) {
    __syncthreads();
#pragma unroll
    for (int st = 0; st < 4; ++st) {
      async_load16(gA + (size_t)(st * 32) * Kld + k0, lA + st * 2048);
      async_load16(gB + (size_t)(st * 32) * Kld + k0, lB + st * 2048);
    }
    __syncthreads();

#pragma unroll
    for (int ks = 0; ks < 2; ++ks) {
      short8 af[4], bfr[4];
#pragma unroll
      for (int t = 0; t < 4; ++t) {
        const int cg = ((ks * 4 + quad) ^ swzb) * 8;
        af[t] = *(const short8*)(sA + (wm + t * 16 + l15) * 64 + cg);
        bfr[t] = *(const short8*)(sB + (wn + t * 16 + l15) * 64 + cg);
      }
#pragma unroll
      for (int mt = 0; mt < 4; ++mt)
#pragma unroll
        for (int nt = 0; nt < 4; ++nt)
          acc[mt][nt] = __builtin_amdgcn_mfma_f32_16x16x32_bf16(
              af[mt], bfr[nt], acc[mt][nt], 0, 0, 0);
    }
  }

  if (EPI == EPI_QKV && n0 >= 2048) {
    // ---- V block: transpose 128x128 tile via LDS -> Vt[bh][d][s] ----
    __syncthreads();  // everyone done with sA/sB ds_reads
#pragma unroll
    for (int nt = 0; nt < 4; ++nt) {
      const int col = n0 + wn + nt * 16 + l15;
      const float bv = bias[col];
#pragma unroll
      for (int mt = 0; mt < 4; ++mt)
#pragma unroll
        for (int r = 0; r < 4; ++r)
          smem[(wn + nt * 16 + l15) * 136 + wm + mt * 16 + quad * 4 + r] =
              f2bf(acc[mt][nt][r] + bv);
    }
    __syncthreads();
    const int vc0 = n0 - 2048;
    const int bb = m0 >> 10;
    const int s0 = m0 & 1023;
#pragma unroll
    for (int i = 0; i < 8; ++i) {
      const int c = i * 16 + (tid >> 4);   // tile channel 0..127
      const int tc = tid & 15;             // token chunk (8 tokens)
      const short8 val = *(const short8*)(smem + c * 136 + tc * 8);
      const int ch = vc0 + c;
      const int hh = ch >> 6, dd = ch & 63;
      *(short8*)(Vt + ((size_t)(bb * 16 + hh) * HD_ + dd) * S_ + s0 + tc * 8) =
          val;
    }
    return;
  }

#pragma unroll
  for (int nt = 0; nt < 4; ++nt) {
    const int col = n0 + wn + nt * 16 + l15;
    const float bv = (EPI == EPI_PARTIAL) ? 0.f : bias[col];
    const float scl = (EPI == EPI_QKV && col < 1024) ? QSCALE : 1.0f;
#pragma unroll
    for (int mt = 0; mt < 4; ++mt) {
#pragma unroll
      for (int r = 0; r < 4; ++r) {
        const int row = m0 + wm + mt * 16 + quad * 4 + r;
        float v = acc[mt][nt][r] + bv;
        if (EPI == EPI_F32) {
          ((float*)Cp)[(size_t)row * N + col] = v;
        } else if (EPI == EPI_PARTIAL) {
          ((float*)Cp)[(size_t)blockIdx.z * M * N + (size_t)row * N + col] = v;
        } else if (EPI == EPI_RELU_BF16) {
          ((unsigned short*)Cp)[(size_t)row * N + col] = f2bf(fmaxf(v, 0.f));
        } else {  // EPI_QKV Q/K: token-major store
          ((unsigned short*)Cp)[(size_t)row * N + col] = f2bf(v * scl);
        }
      }
    }
  }
}

// ---------------------------------------------------------------------------
// Flash attention v5: grid (bh=64, qtile=8), 4 waves x 32 q-rows; K staged
// from token-major Cqkv, V from Vt; fixed-base exp2 softmax; deferred
// row-sum; XOR chunk swizzles.
// ---------------------------------------------------------------------------
__global__ __launch_bounds__(256, 2) void flash_attn(
    const unsigned short* __restrict__ Cqkv, const unsigned short* __restrict__ Vt,
    const unsigned long long* __restrict__ mbits,
    const unsigned int* __restrict__ mrowflag,
    unsigned short* __restrict__ ctx) {
  __shared__ unsigned short sK[128 * 64];
  __shared__ unsigned short sV[64 * 128];
  __shared__ unsigned short spb[4][32 * 136];

  const int tid = threadIdx.x;
  const int wave = tid >> 6;
  const int lane = tid & 63;
  const int quad = lane >> 4;
  const int l15 = lane & 15;
  const int bh = blockIdx.x;
  const int b = bh >> 4;
  const int h = bh & 15;
  const int qbase = blockIdx.y * 128 + wave * 32;

  const unsigned short* Qb = Cqkv + (size_t)(b * S_) * 3072 + h * HD_;
  const unsigned short* Kb = Cqkv + (size_t)(b * S_) * 3072 + DM_ + h * HD_;
  const unsigned short* Vb = Vt + (size_t)bh * HD_ * S_;
  unsigned short* pbuf = spb[wave];

  bool mask_all_ones;
  {
    unsigned int f = mrowflag[b * S_ + qbase + (lane & 31)];
    mask_all_ones = (__ballot(f != 0) == ~0ull);
  }

  short8 qf[2][2];
#pragma unroll
  for (int u = 0; u < 2; ++u)
#pragma unroll
    for (int ks = 0; ks < 2; ++ks)
      qf[u][ks] = *(const short8*)(Qb + (size_t)(qbase + u * 16 + l15) * 3072 +
                                   ks * 32 + quad * 8);

  f32x4 o[2][4];
#pragma unroll
  for (int u = 0; u < 2; ++u)
#pragma unroll
    for (int i = 0; i < 4; ++i) o[u][i] = (f32x4){0.f, 0.f, 0.f, 0.f};
  float lsum[2][4] = {{0.f, 0.f, 0.f, 0.f}, {0.f, 0.f, 0.f, 0.f}};

  for (int kt = 0; kt < S_ / 128; ++kt) {
    const int kbase = kt * 128;

    __syncthreads();
#pragma unroll
    for (int st = 0; st < 4; ++st) {
      const int j = st * 256 + tid;
      const int r = j >> 3, c = j & 7;
      async_load16(Kb + (size_t)(kbase + r) * 3072 + ((c ^ (r & 7)) * 8),
                   sK + j * 8);
    }
#pragma unroll
    for (int st = 0; st < 4; ++st) {
      const int j = st * 256 + tid;
      const int d = j >> 4, c = j & 15;
      async_load16(Vb + (size_t)d * S_ + kbase + ((c ^ (d & 15)) * 8),
                   sV + j * 8);
    }
    __syncthreads();

    f32x4 s[2][8];
#pragma unroll
    for (int u = 0; u < 2; ++u)
#pragma unroll
      for (int i = 0; i < 8; ++i) s[u][i] = (f32x4){0.f, 0.f, 0.f, 0.f};
#pragma unroll
    for (int ks = 0; ks < 2; ++ks) {
      const int cg = ks * 4 + quad;
#pragma unroll
      for (int nt = 0; nt < 8; ++nt) {
        const int row = nt * 16 + l15;
        const short8 kf =
            *(const short8*)(sK + row * 64 + ((cg ^ (row & 7)) * 8));
        s[0][nt] = __builtin_amdgcn_mfma_f32_16x16x32_bf16(qf[0][ks], kf,
                                                           s[0][nt], 0, 0, 0);
        s[1][nt] = __builtin_amdgcn_mfma_f32_16x16x32_bf16(qf[1][ks], kf,
                                                           s[1][nt], 0, 0, 0);
      }
    }

    if (!mask_all_ones) {
#pragma unroll
      for (int u = 0; u < 2; ++u)
#pragma unroll
        for (int r = 0; r < 4; ++r) {
          const int q = qbase + u * 16 + quad * 4 + r;
          const unsigned long long* wp =
              mbits + ((size_t)(b * S_ + q)) * 16 + kt * 2;
          const unsigned long long w0 = wp[0], w1 = wp[1];
#pragma unroll
          for (int nt = 0; nt < 8; ++nt) {
            const unsigned long long w = (nt < 4) ? w0 : w1;
            const int bit = (nt * 16 + l15) & 63;
            if (!((w >> bit) & 1)) s[u][nt][r] = -1.0e8f;
          }
        }
    }

#pragma unroll
    for (int u = 0; u < 2; ++u)
#pragma unroll
      for (int nt = 0; nt < 8; ++nt)
#pragma unroll
        for (int r = 0; r < 4; ++r) {
          const float p = __builtin_amdgcn_exp2f(s[u][nt][r]);
          lsum[u][r] += p;
          pbuf[(u * 16 + quad * 4 + r) * 136 + nt * 16 + l15] = f2bf(p);
        }

#pragma unroll
    for (int ks2 = 0; ks2 < 4; ++ks2) {
      const short8 pf0 =
          *(const short8*)(pbuf + l15 * 136 + ks2 * 32 + quad * 8);
      const short8 pf1 =
          *(const short8*)(pbuf + (16 + l15) * 136 + ks2 * 32 + quad * 8);
      const int cg = ks2 * 4 + quad;
#pragma unroll
      for (int nt = 0; nt < 4; ++nt) {
        const int d = nt * 16 + l15;
        const short8 vf =
            *(const short8*)(sV + d * 128 + ((cg ^ (d & 15)) * 8));
        o[0][nt] = __builtin_amdgcn_mfma_f32_16x16x32_bf16(pf0, vf, o[0][nt], 0, 0, 0);
        o[1][nt] = __builtin_amdgcn_mfma_f32_16x16x32_bf16(pf1, vf, o[1][nt], 0, 0, 0);
      }
    }
  }

#pragma unroll
  for (int u = 0; u < 2; ++u)
#pragma unroll
    for (int r = 0; r < 4; ++r) {
      float lr = lsum[u][r];
      lr += __shfl_xor(lr, 1);
      lr += __shfl_xor(lr, 2);
      lr += __shfl_xor(lr, 4);
      lr += __shfl_xor(lr, 8);
      const float inv = 1.0f / lr;
#pragma unroll
      for (int nt = 0; nt < 4; ++nt)
        pbuf[(u * 16 + quad * 4 + r) * 68 + nt * 16 + l15] =
            f2bf(o[u][nt][r] * inv);
    }
#pragma unroll
  for (int i = 0; i < 4; ++i) {
    const int j = i * 64 + lane;
    const int r = j >> 3, c = j & 7;
    const short8 val = *(const short8*)(pbuf + r * 68 + c * 8);
    *(short8*)(ctx + ((size_t)b * S_ + qbase + r) * DM_ + h * HD_ + c * 8) = val;
  }
}

// ---------------------------------------------------------------------------
// FFN2 split-K reduce: out = part[0] + part[1] + b2
// ---------------------------------------------------------------------------
__global__ void reduce_ffn2_kernel(const float* __restrict__ part,
                                   const float* __restrict__ b2,
                                   float* __restrict__ out) {
  const int i = blockIdx.x * 256 + threadIdx.x;
  const f32x4 a = ((const f32x4*)part)[i];
  const f32x4 b = ((const f32x4*)part)[i + (B_ * S_ * DM_ / 4)];
  const f32x4 bb = ((const f32x4*)b2)[i & 255];
  ((f32x4*)out)[i] = a + b + bb;
}

// ---------------------------------------------------------------------------
// launch
// ---------------------------------------------------------------------------
extern "C" void kernel_launch(void* const* d_in, const int* in_sizes, int n_in,
                              void* d_out, int out_size, void* d_ws,
                              size_t ws_size, hipStream_t stream) {
  const float* x = (const float*)d_in[0];
  const float* Wq = (const float*)d_in[1];
  const float* bq = (const float*)d_in[2];
  const float* Wk = (const float*)d_in[3];
  const float* bk = (const float*)d_in[4];
  const float* Wv = (const float*)d_in[5];
  const float* bv = (const float*)d_in[6];
  const float* W1 = (const float*)d_in[7];
  const float* b1 = (const float*)d_in[8];
  const float* W2 = (const float*)d_in[9];
  const float* b2 = (const float*)d_in[10];
  const int* mask = (const int*)d_in[11];
  float* out = (float*)d_out;

  char* ws = (char*)d_ws;
  unsigned short* xb   = (unsigned short*)(ws + 0);          //  8 MB
  unsigned short* wqkv = (unsigned short*)(ws + 8388608);    //  6 MB
  unsigned short* w1b  = (unsigned short*)(ws + 14680064);   //  4 MB
  unsigned short* w2b  = (unsigned short*)(ws + 18874368);   //  4 MB
  unsigned short* Cqkv = (unsigned short*)(ws + 23068672);   // 24 MB [4096,3072]
  unsigned short* ctxb = (unsigned short*)(ws + 48234496);   //  8 MB
  unsigned short* hb   = (unsigned short*)(ws + 56623104);   // 16 MB
  // Vt lives in hb's first 8 MB: hb is dead until FFN1, which runs after
  // flash_attn has fully consumed Vt. Keeps ws footprint at R5's proven level.
  unsigned short* Vt   = (unsigned short*)(ws + 56623104);   //  8 MB [B,H,64,S]
  unsigned long long* mbits = (unsigned long long*)(ws + 73400320);  // 512 KB
  unsigned int* mrowflag    = (unsigned int*)(ws + 73924608);        //  16 KB
  float* cb                 = (float*)(ws + 73940992);               //  12 KB
  float* part = (float*)(ws + 23068672);  // 32 MB (Cqkv+ctxb dead by FFN2)

  PrepArgs pa;
  pa.src[0] = x;  pa.dst[0] = xb;               pa.n4[0] = (B_ * S_ * DM_) / 4;
  pa.src[1] = Wq; pa.dst[1] = wqkv;             pa.n4[1] = (DM_ * DM_) / 4;
  pa.src[2] = Wk; pa.dst[2] = wqkv + DM_ * DM_; pa.n4[2] = (DM_ * DM_) / 4;
  pa.src[3] = Wv; pa.dst[3] = wqkv + 2 * DM_ * DM_; pa.n4[3] = (DM_ * DM_) / 4;
  pa.src[4] = W1; pa.dst[4] = w1b;              pa.n4[4] = (2 * DM_ * DM_) / 4;
  pa.src[5] = W2; pa.dst[5] = w2b;              pa.n4[5] = (2 * DM_ * DM_) / 4;
  pa.mask = mask; pa.bits = mbits; pa.rowflag = mrowflag;
  pa.bq = bq; pa.bk = bk; pa.bv = bv; pa.cb = cb;
  prep_kernel<<<dim3(256, 8), 256, 0, stream>>>(pa);

  const int M = B_ * S_;  // 4096
  // QKV projection: Q/K -> token-major Cqkv (Q pre-scaled); V -> Vt transposed
  gemm_bt<EPI_QKV><<<dim3(3 * DM_ / 128, M / 128), 256, 0, stream>>>(
      xb, wqkv, cb, Cqkv, Vt, M, 3 * DM_, DM_, DM_);

  flash_attn<<<dim3(B_ * H_, S_ / 128), 256, 0, stream>>>(
      Cqkv, Vt, mbits, mrowflag, ctxb);

  gemm_bt<EPI_RELU_BF16><<<dim3((2 * DM_) / 128, M / 128), 256, 0, stream>>>(
      ctxb, w1b, b1, hb, nullptr, M, 2 * DM_, DM_, DM_);

  gemm_bt<EPI_PARTIAL><<<dim3(DM_ / 128, M / 128, 2), 256, 0, stream>>>(
      hb, w2b, b2, part, nullptr, M, DM_, DM_, 2 * DM_);
  reduce_ffn2_kernel<<<dim3(M * DM_ / 4 / 256), 256, 0, stream>>>(part, b2, out);
}

// Round 8
// 247.930 us; speedup vs baseline: 1.0325x; 1.0325x over previous
//
#include <hip/hip_runtime.h>
#include <hip/hip_bf16.h>
#include <stdint.h>

// ---------------------------------------------------------------------------
// MultiHeadSelfAttention: x[4,1024,1024] fp32 -> out[4,1024,1024] fp32
// R8: (1) vectorized mask pack (1 row/wave, int4 loads, shfl-compose) in a
// balanced (1024,8) prep grid; (2) flash LDS 67->49.4 KB (per-wave P buffer
// halved, PV per q-subtile) -> 3 blocks/CU. Everything else as R7.
// ---------------------------------------------------------------------------

#define B_ 4
#define S_ 1024
#define DM_ 1024
#define H_ 16
#define HD_ 64

typedef __attribute__((ext_vector_type(8))) short short8;
typedef __attribute__((ext_vector_type(4))) float f32x4;
typedef __attribute__((ext_vector_type(4))) unsigned short ushort4v;

#define GLB_AS(p) ((const __attribute__((address_space(1))) void*)(p))
#define LDS_AS(p) ((__attribute__((address_space(3))) void*)(p))

__device__ __forceinline__ void async_load16(const void* g, void* l) {
  __builtin_amdgcn_global_load_lds(GLB_AS(g), LDS_AS(l), 16, 0, 0);
}

__device__ __forceinline__ unsigned short f2bf(float x) {
  union { float f; unsigned int u; } v; v.f = x;
  unsigned int r = v.u + 0x7fffu + ((v.u >> 16) & 1u);  // RNE
  return (unsigned short)(r >> 16);
}

// 0.125 (1/sqrt(64)) * log2(e): folds softmax scale + exp->exp2 into Q proj.
#define QSCALE 0.18033688011112042f

// ---------------------------------------------------------------------------
// Fused prep: seg 0..5 fp32->bf16 convert; seg 6 mask pack; seg 7 bias concat
// grid (1024, 8)
// ---------------------------------------------------------------------------
struct PrepArgs {
  const float* src[6];
  unsigned short* dst[6];
  int n4[6];
  const int* mask;
  unsigned long long* bits;
  unsigned int* rowflag;
  const float* bq;
  const float* bk;
  const float* bv;
  float* cb;
};

__global__ void prep_kernel(PrepArgs a) {
  const int seg = blockIdx.y;
  if (seg < 6) {
    const int n4 = a.n4[seg];
    const f32x4* __restrict__ src = (const f32x4*)a.src[seg];
    ushort4v* __restrict__ dst = (ushort4v*)a.dst[seg];
    for (int i = blockIdx.x * blockDim.x + threadIdx.x; i < n4;
         i += gridDim.x * blockDim.x) {
      f32x4 v = src[i];
      ushort4v o;
      o[0] = f2bf(v[0]); o[1] = f2bf(v[1]); o[2] = f2bf(v[2]); o[3] = f2bf(v[3]);
      dst[i] = o;
    }
  } else if (seg == 6) {
    // mask pack: 1 row per wave (4 rows/block x 1024 blocks).
    // lane i covers mask positions [16i,16i+16) via 4 independent int4 loads.
    const int wave = threadIdx.x >> 6;
    const int lane = threadIdx.x & 63;
    const int row = blockIdx.x * 4 + wave;
    const int4* mr = (const int4*)(a.mask + (size_t)row * S_) + lane * 4;
    unsigned int chunk = 0;
#pragma unroll
    for (int t = 0; t < 4; ++t) {
      const int4 v = mr[t];
      chunk |= (v.x != 0 ? 1u : 0u) << (4 * t + 0);
      chunk |= (v.y != 0 ? 1u : 0u) << (4 * t + 1);
      chunk |= (v.z != 0 ? 1u : 0u) << (4 * t + 2);
      chunk |= (v.w != 0 ? 1u : 0u) << (4 * t + 3);
    }
    // compose u64 word g from lanes 4g..4g+3 (butterfly within groups of 4)
    unsigned long long v64 = (unsigned long long)chunk << (16 * (lane & 3));
    v64 |= __shfl_xor(v64, 1);
    v64 |= __shfl_xor(v64, 2);
    if ((lane & 3) == 0) a.bits[(size_t)row * 16 + (lane >> 2)] = v64;
    const bool all1 = (__ballot(chunk == 0xffffu) == ~0ull);
    if (lane == 0) a.rowflag[row] = all1 ? 1u : 0u;
  } else {
    const int i = blockIdx.x * 256 + threadIdx.x;
    if (i < 3072) {
      const float* src = (i < 1024) ? a.bq : (i < 2048) ? a.bk : a.bv;
      a.cb[i] = src[i & 1023];
    }
  }
}

// ---------------------------------------------------------------------------
// NT GEMM, BK=64, XOR chunk swizzle. EPI_QKV: Q/K token-major into Cqkv
// (Q pre-scaled); V blocks (n0>=2048) transposed in-epilogue -> Vt[bh][d][s].
// ---------------------------------------------------------------------------
enum { EPI_QKV = 0, EPI_RELU_BF16 = 2, EPI_F32 = 3, EPI_PARTIAL = 4 };

template <int EPI>
__global__ __launch_bounds__(256, 3) void gemm_bt(
    const unsigned short* __restrict__ A, const unsigned short* __restrict__ Bt,
    const float* __restrict__ bias, void* __restrict__ Cp,
    unsigned short* __restrict__ Vt, int M, int N, int K, int Kld) {
  // 34816 B. Main loop: sA = smem[0..8192), sB = smem[8192..16384) (shorts).
  // V-epilogue reuses the whole buffer (after barrier) as a 128x136 tile.
  __shared__ __align__(16) unsigned short smem[128 * 136];
  unsigned short* sA = smem;
  unsigned short* sB = smem + 128 * 64;

  const int tid = threadIdx.x;
  const int lane = tid & 63;
  const int wave = tid >> 6;
  const int quad = lane >> 4;
  const int l15 = lane & 15;
  const int swzb = l15 & 7;
  const int m0 = blockIdx.y * 128;
  const int n0 = blockIdx.x * 128;
  const int wm = (wave >> 1) * 64;
  const int wn = (wave & 1) * 64;
  const int kz = blockIdx.z * K;

  f32x4 acc[4][4];
#pragma unroll
  for (int i = 0; i < 4; ++i)
#pragma unroll
    for (int j = 0; j < 4; ++j) acc[i][j] = (f32x4){0.f, 0.f, 0.f, 0.f};

  const int srow = tid >> 3;
  const int scol = ((tid & 7) ^ (srow & 7)) * 8;
  const unsigned short* gA = A + (size_t)(m0 + srow) * Kld + kz + scol;
  const unsigned short* gB = Bt + (size_t)(n0 + srow) * Kld + kz + scol;
  unsigned short* lA = sA + tid * 8;
  unsigned short* lB = sB + tid * 8;

  for (int k0 = 0; k0 < K; k0 += 64) {
    __syncthreads();
#pragma unroll
    for (int st = 0; st < 4; ++st) {
      async_load16(gA + (size_t)(st * 32) * Kld + k0, lA + st * 2048);
      async_load16(gB + (size_t)(st * 32) * Kld + k0, lB + st * 2048);
    }
    __syncthreads();

#pragma unroll
    for (int ks = 0; ks < 2; ++ks) {
      short8 af[4], bfr[4];
#pragma unroll
      for (int t = 0; t < 4; ++t) {
        const int cg = ((ks * 4 + quad) ^ swzb) * 8;
        af[t] = *(const short8*)(sA + (wm + t * 16 + l15) * 64 + cg);
        bfr[t] = *(const short8*)(sB + (wn + t * 16 + l15) * 64 + cg);
      }
#pragma unroll
      for (int mt = 0; mt < 4; ++mt)
#pragma unroll
        for (int nt = 0; nt < 4; ++nt)
          acc[mt][nt] = __builtin_amdgcn_mfma_f32_16x16x32_bf16(
              af[mt], bfr[nt], acc[mt][nt], 0, 0, 0);
    }
  }

  if (EPI == EPI_QKV && n0 >= 2048) {
    // ---- V block: transpose 128x128 tile via LDS -> Vt[bh][d][s] ----
    __syncthreads();
#pragma unroll
    for (int nt = 0; nt < 4; ++nt) {
      const int col = n0 + wn + nt * 16 + l15;
      const float bv = bias[col];
#pragma unroll
      for (int mt = 0; mt < 4; ++mt)
#pragma unroll
        for (int r = 0; r < 4; ++r)
          smem[(wn + nt * 16 + l15) * 136 + wm + mt * 16 + quad * 4 + r] =
              f2bf(acc[mt][nt][r] + bv);
    }
    __syncthreads();
    const int vc0 = n0 - 2048;
    const int bb = m0 >> 10;
    const int s0 = m0 & 1023;
#pragma unroll
    for (int i = 0; i < 8; ++i) {
      const int c = i * 16 + (tid >> 4);
      const int tc = tid & 15;
      const short8 val = *(const short8*)(smem + c * 136 + tc * 8);
      const int ch = vc0 + c;
      const int hh = ch >> 6, dd = ch & 63;
      *(short8*)(Vt + ((size_t)(bb * 16 + hh) * HD_ + dd) * S_ + s0 + tc * 8) =
          val;
    }
    return;
  }

#pragma unroll
  for (int nt = 0; nt < 4; ++nt) {
    const int col = n0 + wn + nt * 16 + l15;
    const float bv = (EPI == EPI_PARTIAL) ? 0.f : bias[col];
    const float scl = (EPI == EPI_QKV && col < 1024) ? QSCALE : 1.0f;
#pragma unroll
    for (int mt = 0; mt < 4; ++mt) {
#pragma unroll
      for (int r = 0; r < 4; ++r) {
        const int row = m0 + wm + mt * 16 + quad * 4 + r;
        float v = acc[mt][nt][r] + bv;
        if (EPI == EPI_F32) {
          ((float*)Cp)[(size_t)row * N + col] = v;
        } else if (EPI == EPI_PARTIAL) {
          ((float*)Cp)[(size_t)blockIdx.z * M * N + (size_t)row * N + col] = v;
        } else if (EPI == EPI_RELU_BF16) {
          ((unsigned short*)Cp)[(size_t)row * N + col] = f2bf(fmaxf(v, 0.f));
        } else {  // EPI_QKV Q/K: token-major store
          ((unsigned short*)Cp)[(size_t)row * N + col] = f2bf(v * scl);
        }
      }
    }
  }
}

// ---------------------------------------------------------------------------
// Flash attention v6: grid (bh=64, qtile=8), 4 waves x 32 q-rows; per-wave
// P buffer is 16x136 (one q-subtile), PV done per subtile -> LDS 49.4 KB,
// 3 blocks/CU. K from token-major Cqkv, V from Vt; fixed-base exp2 softmax.
// ---------------------------------------------------------------------------
__global__ __launch_bounds__(256, 3) void flash_attn(
    const unsigned short* __restrict__ Cqkv, const unsigned short* __restrict__ Vt,
    const unsigned long long* __restrict__ mbits,
    const unsigned int* __restrict__ mrowflag,
    unsigned short* __restrict__ ctx) {
  __shared__ unsigned short sK[128 * 64];      // 16 KB
  __shared__ unsigned short sV[64 * 128];      // 16 KB
  __shared__ unsigned short spb[4][16 * 136];  // 17 KB (per-wave 16x128 tile)

  const int tid = threadIdx.x;
  const int wave = tid >> 6;
  const int lane = tid & 63;
  const int quad = lane >> 4;
  const int l15 = lane & 15;
  const int bh = blockIdx.x;
  const int b = bh >> 4;
  const int h = bh & 15;
  const int qbase = blockIdx.y * 128 + wave * 32;

  const unsigned short* Qb = Cqkv + (size_t)(b * S_) * 3072 + h * HD_;
  const unsigned short* Kb = Cqkv + (size_t)(b * S_) * 3072 + DM_ + h * HD_;
  const unsigned short* Vb = Vt + (size_t)bh * HD_ * S_;
  unsigned short* pbuf = spb[wave];

  bool mask_all_ones;
  {
    unsigned int f = mrowflag[b * S_ + qbase + (lane & 31)];
    mask_all_ones = (__ballot(f != 0) == ~0ull);
  }

  short8 qf[2][2];
#pragma unroll
  for (int u = 0; u < 2; ++u)
#pragma unroll
    for (int ks = 0; ks < 2; ++ks)
      qf[u][ks] = *(const short8*)(Qb + (size_t)(qbase + u * 16 + l15) * 3072 +
                                   ks * 32 + quad * 8);

  f32x4 o[2][4];
#pragma unroll
  for (int u = 0; u < 2; ++u)
#pragma unroll
    for (int i = 0; i < 4; ++i) o[u][i] = (f32x4){0.f, 0.f, 0.f, 0.f};
  float lsum[2][4] = {{0.f, 0.f, 0.f, 0.f}, {0.f, 0.f, 0.f, 0.f}};

  for (int kt = 0; kt < S_ / 128; ++kt) {
    const int kbase = kt * 128;

    __syncthreads();
#pragma unroll
    for (int st = 0; st < 4; ++st) {
      const int j = st * 256 + tid;
      const int r = j >> 3, c = j & 7;
      async_load16(Kb + (size_t)(kbase + r) * 3072 + ((c ^ (r & 7)) * 8),
                   sK + j * 8);
    }
#pragma unroll
    for (int st = 0; st < 4; ++st) {
      const int j = st * 256 + tid;
      const int d = j >> 4, c = j & 15;
      async_load16(Vb + (size_t)d * S_ + kbase + ((c ^ (d & 15)) * 8),
                   sV + j * 8);
    }
    __syncthreads();

    f32x4 s[2][8];
#pragma unroll
    for (int u = 0; u < 2; ++u)
#pragma unroll
      for (int i = 0; i < 8; ++i) s[u][i] = (f32x4){0.f, 0.f, 0.f, 0.f};
#pragma unroll
    for (int ks = 0; ks < 2; ++ks) {
      const int cg = ks * 4 + quad;
#pragma unroll
      for (int nt = 0; nt < 8; ++nt) {
        const int row = nt * 16 + l15;
        const short8 kf =
            *(const short8*)(sK + row * 64 + ((cg ^ (row & 7)) * 8));
        s[0][nt] = __builtin_amdgcn_mfma_f32_16x16x32_bf16(qf[0][ks], kf,
                                                           s[0][nt], 0, 0, 0);
        s[1][nt] = __builtin_amdgcn_mfma_f32_16x16x32_bf16(qf[1][ks], kf,
                                                           s[1][nt], 0, 0, 0);
      }
    }

    if (!mask_all_ones) {
#pragma unroll
      for (int u = 0; u < 2; ++u)
#pragma unroll
        for (int r = 0; r < 4; ++r) {
          const int q = qbase + u * 16 + quad * 4 + r;
          const unsigned long long* wp =
              mbits + ((size_t)(b * S_ + q)) * 16 + kt * 2;
          const unsigned long long w0 = wp[0], w1 = wp[1];
#pragma unroll
          for (int nt = 0; nt < 8; ++nt) {
            const unsigned long long w = (nt < 4) ? w0 : w1;
            const int bit = (nt * 16 + l15) & 63;
            if (!((w >> bit) & 1)) s[u][nt][r] = -1.0e8f;
          }
        }
    }

    // ---- per q-subtile: P -> wave-private LDS -> PV MFMA (in-order DS
    // within the wave makes u=1's writes safe after u=0's reads) ----
#pragma unroll
    for (int u = 0; u < 2; ++u) {
#pragma unroll
      for (int nt = 0; nt < 8; ++nt)
#pragma unroll
        for (int r = 0; r < 4; ++r) {
          const float p = __builtin_amdgcn_exp2f(s[u][nt][r]);
          lsum[u][r] += p;
          pbuf[(quad * 4 + r) * 136 + nt * 16 + l15] = f2bf(p);
        }
#pragma unroll
      for (int ks2 = 0; ks2 < 4; ++ks2) {
        const short8 pf =
            *(const short8*)(pbuf + l15 * 136 + ks2 * 32 + quad * 8);
        const int cg = ks2 * 4 + quad;
#pragma unroll
        for (int nt = 0; nt < 4; ++nt) {
          const int d = nt * 16 + l15;
          const short8 vf =
              *(const short8*)(sV + d * 128 + ((cg ^ (d & 15)) * 8));
          o[u][nt] =
              __builtin_amdgcn_mfma_f32_16x16x32_bf16(pf, vf, o[u][nt], 0, 0, 0);
        }
      }
    }
  }

  // ---- finalize: reduce row sums, normalize, repack (32x68 fits exactly
  // in the 16x136 = 2176-short per-wave buffer), coalesced 16B stores ----
#pragma unroll
  for (int u = 0; u < 2; ++u)
#pragma unroll
    for (int r = 0; r < 4; ++r) {
      float lr = lsum[u][r];
      lr += __shfl_xor(lr, 1);
      lr += __shfl_xor(lr, 2);
      lr += __shfl_xor(lr, 4);
      lr += __shfl_xor(lr, 8);
      const float inv = 1.0f / lr;
#pragma unroll
      for (int nt = 0; nt < 4; ++nt)
        pbuf[(u * 16 + quad * 4 + r) * 68 + nt * 16 + l15] =
            f2bf(o[u][nt][r] * inv);
    }
#pragma unroll
  for (int i = 0; i < 4; ++i) {
    const int j = i * 64 + lane;
    const int r = j >> 3, c = j & 7;
    const short8 val = *(const short8*)(pbuf + r * 68 + c * 8);
    *(short8*)(ctx + ((size_t)b * S_ + qbase + r) * DM_ + h * HD_ + c * 8) = val;
  }
}

// ---------------------------------------------------------------------------
// FFN2 split-K reduce: out = part[0] + part[1] + b2
// ---------------------------------------------------------------------------
__global__ void reduce_ffn2_kernel(const float* __restrict__ part,
                                   const float* __restrict__ b2,
                                   float* __restrict__ out) {
  const int i = blockIdx.x * 256 + threadIdx.x;
  const f32x4 a = ((const f32x4*)part)[i];
  const f32x4 b = ((const f32x4*)part)[i + (B_ * S_ * DM_ / 4)];
  const f32x4 bb = ((const f32x4*)b2)[i & 255];
  ((f32x4*)out)[i] = a + b + bb;
}

// ---------------------------------------------------------------------------
// launch
// ---------------------------------------------------------------------------
extern "C" void kernel_launch(void* const* d_in, const int* in_sizes, int n_in,
                              void* d_out, int out_size, void* d_ws,
                              size_t ws_size, hipStream_t stream) {
  const float* x = (const float*)d_in[0];
  const float* Wq = (const float*)d_in[1];
  const float* bq = (const float*)d_in[2];
  const float* Wk = (const float*)d_in[3];
  const float* bk = (const float*)d_in[4];
  const float* Wv = (const float*)d_in[5];
  const float* bv = (const float*)d_in[6];
  const float* W1 = (const float*)d_in[7];
  const float* b1 = (const float*)d_in[8];
  const float* W2 = (const float*)d_in[9];
  const float* b2 = (const float*)d_in[10];
  const int* mask = (const int*)d_in[11];
  float* out = (float*)d_out;

  char* ws = (char*)d_ws;
  unsigned short* xb   = (unsigned short*)(ws + 0);          //  8 MB
  unsigned short* wqkv = (unsigned short*)(ws + 8388608);    //  6 MB
  unsigned short* w1b  = (unsigned short*)(ws + 14680064);   //  4 MB
  unsigned short* w2b  = (unsigned short*)(ws + 18874368);   //  4 MB
  unsigned short* Cqkv = (unsigned short*)(ws + 23068672);   // 24 MB [4096,3072]
  unsigned short* ctxb = (unsigned short*)(ws + 48234496);   //  8 MB
  unsigned short* hb   = (unsigned short*)(ws + 56623104);   // 16 MB
  // Vt lives in hb's first 8 MB: hb is dead until FFN1, which runs after
  // flash_attn has fully consumed Vt.
  unsigned short* Vt   = (unsigned short*)(ws + 56623104);   //  8 MB [B,H,64,S]
  unsigned long long* mbits = (unsigned long long*)(ws + 73400320);  // 512 KB
  unsigned int* mrowflag    = (unsigned int*)(ws + 73924608);        //  16 KB
  float* cb                 = (float*)(ws + 73940992);               //  12 KB
  float* part = (float*)(ws + 23068672);  // 32 MB (Cqkv+ctxb dead by FFN2)

  PrepArgs pa;
  pa.src[0] = x;  pa.dst[0] = xb;               pa.n4[0] = (B_ * S_ * DM_) / 4;
  pa.src[1] = Wq; pa.dst[1] = wqkv;             pa.n4[1] = (DM_ * DM_) / 4;
  pa.src[2] = Wk; pa.dst[2] = wqkv + DM_ * DM_; pa.n4[2] = (DM_ * DM_) / 4;
  pa.src[3] = Wv; pa.dst[3] = wqkv + 2 * DM_ * DM_; pa.n4[3] = (DM_ * DM_) / 4;
  pa.src[4] = W1; pa.dst[4] = w1b;              pa.n4[4] = (2 * DM_ * DM_) / 4;
  pa.src[5] = W2; pa.dst[5] = w2b;              pa.n4[5] = (2 * DM_ * DM_) / 4;
  pa.mask = mask; pa.bits = mbits; pa.rowflag = mrowflag;
  pa.bq = bq; pa.bk = bk; pa.bv = bv; pa.cb = cb;
  prep_kernel<<<dim3(1024, 8), 256, 0, stream>>>(pa);

  const int M = B_ * S_;  // 4096
  gemm_bt<EPI_QKV><<<dim3(3 * DM_ / 128, M / 128), 256, 0, stream>>>(
      xb, wqkv, cb, Cqkv, Vt, M, 3 * DM_, DM_, DM_);

  flash_attn<<<dim3(B_ * H_, S_ / 128), 256, 0, stream>>>(
      Cqkv, Vt, mbits, mrowflag, ctxb);

  gemm_bt<EPI_RELU_BF16><<<dim3((2 * DM_) / 128, M / 128), 256, 0, stream>>>(
      ctxb, w1b, b1, hb, nullptr, M, 2 * DM_, DM_, DM_);

  gemm_bt<EPI_PARTIAL><<<dim3(DM_ / 128, M / 128, 2), 256, 0, stream>>>(
      hb, w2b, b2, part, nullptr, M, DM_, DM_, 2 * DM_);
  reduce_ffn2_kernel<<<dim3(M * DM_ / 4 / 256), 256, 0, stream>>>(part, b2, out);
}

// Round 9
// 231.152 us; speedup vs baseline: 1.1074x; 1.0726x over previous
//
#include <hip/hip_runtime.h>
#include <hip/hip_bf16.h>
#include <stdint.h>

// ---------------------------------------------------------------------------
// MultiHeadSelfAttention: x[4,1024,1024] fp32 -> out[4,1024,1024] fp32
// R9: flash reverted to R7 structure (P 32x136, shared V-frag PV, 2 blk/CU);
// FFN2 = intra-block split-K (512 thr, LDS combine) -> no partial traffic,
// no reduce kernel. 5 dispatches.
// ---------------------------------------------------------------------------

#define B_ 4
#define S_ 1024
#define DM_ 1024
#define H_ 16
#define HD_ 64

typedef __attribute__((ext_vector_type(8))) short short8;
typedef __attribute__((ext_vector_type(4))) float f32x4;
typedef __attribute__((ext_vector_type(4))) unsigned short ushort4v;

#define GLB_AS(p) ((const __attribute__((address_space(1))) void*)(p))
#define LDS_AS(p) ((__attribute__((address_space(3))) void*)(p))

__device__ __forceinline__ void async_load16(const void* g, void* l) {
  __builtin_amdgcn_global_load_lds(GLB_AS(g), LDS_AS(l), 16, 0, 0);
}

__device__ __forceinline__ unsigned short f2bf(float x) {
  union { float f; unsigned int u; } v; v.f = x;
  unsigned int r = v.u + 0x7fffu + ((v.u >> 16) & 1u);  // RNE
  return (unsigned short)(r >> 16);
}

// 0.125 (1/sqrt(64)) * log2(e): folds softmax scale + exp->exp2 into Q proj.
#define QSCALE 0.18033688011112042f

// ---------------------------------------------------------------------------
// Fused prep: seg 0..5 fp32->bf16 convert; seg 6 mask pack; seg 7 bias concat
// grid (1024, 8)
// ---------------------------------------------------------------------------
struct PrepArgs {
  const float* src[6];
  unsigned short* dst[6];
  int n4[6];
  const int* mask;
  unsigned long long* bits;
  unsigned int* rowflag;
  const float* bq;
  const float* bk;
  const float* bv;
  float* cb;
};

__global__ void prep_kernel(PrepArgs a) {
  const int seg = blockIdx.y;
  if (seg < 6) {
    const int n4 = a.n4[seg];
    const f32x4* __restrict__ src = (const f32x4*)a.src[seg];
    ushort4v* __restrict__ dst = (ushort4v*)a.dst[seg];
    for (int i = blockIdx.x * blockDim.x + threadIdx.x; i < n4;
         i += gridDim.x * blockDim.x) {
      f32x4 v = src[i];
      ushort4v o;
      o[0] = f2bf(v[0]); o[1] = f2bf(v[1]); o[2] = f2bf(v[2]); o[3] = f2bf(v[3]);
      dst[i] = o;
    }
  } else if (seg == 6) {
    // mask pack: 1 row per wave; lane i covers positions [16i,16i+16).
    const int wave = threadIdx.x >> 6;
    const int lane = threadIdx.x & 63;
    const int row = blockIdx.x * 4 + wave;
    const int4* mr = (const int4*)(a.mask + (size_t)row * S_) + lane * 4;
    unsigned int chunk = 0;
#pragma unroll
    for (int t = 0; t < 4; ++t) {
      const int4 v = mr[t];
      chunk |= (v.x != 0 ? 1u : 0u) << (4 * t + 0);
      chunk |= (v.y != 0 ? 1u : 0u) << (4 * t + 1);
      chunk |= (v.z != 0 ? 1u : 0u) << (4 * t + 2);
      chunk |= (v.w != 0 ? 1u : 0u) << (4 * t + 3);
    }
    unsigned long long v64 = (unsigned long long)chunk << (16 * (lane & 3));
    v64 |= __shfl_xor(v64, 1);
    v64 |= __shfl_xor(v64, 2);
    if ((lane & 3) == 0) a.bits[(size_t)row * 16 + (lane >> 2)] = v64;
    const bool all1 = (__ballot(chunk == 0xffffu) == ~0ull);
    if (lane == 0) a.rowflag[row] = all1 ? 1u : 0u;
  } else {
    const int i = blockIdx.x * 256 + threadIdx.x;
    if (i < 3072) {
      const float* src = (i < 1024) ? a.bq : (i < 2048) ? a.bk : a.bv;
      a.cb[i] = src[i & 1023];
    }
  }
}

// ---------------------------------------------------------------------------
// NT GEMM, BK=64, XOR chunk swizzle. EPI_QKV: Q/K token-major into Cqkv
// (Q pre-scaled); V blocks (n0>=2048) transposed in-epilogue -> Vt[bh][d][s].
// ---------------------------------------------------------------------------
enum { EPI_QKV = 0, EPI_RELU_BF16 = 2 };

template <int EPI>
__global__ __launch_bounds__(256, 3) void gemm_bt(
    const unsigned short* __restrict__ A, const unsigned short* __restrict__ Bt,
    const float* __restrict__ bias, void* __restrict__ Cp,
    unsigned short* __restrict__ Vt, int M, int N, int K, int Kld) {
  __shared__ __align__(16) unsigned short smem[128 * 136];
  unsigned short* sA = smem;
  unsigned short* sB = smem + 128 * 64;

  const int tid = threadIdx.x;
  const int lane = tid & 63;
  const int wave = tid >> 6;
  const int quad = lane >> 4;
  const int l15 = lane & 15;
  const int swzb = l15 & 7;
  const int m0 = blockIdx.y * 128;
  const int n0 = blockIdx.x * 128;
  const int wm = (wave >> 1) * 64;
  const int wn = (wave & 1) * 64;

  f32x4 acc[4][4];
#pragma unroll
  for (int i = 0; i < 4; ++i)
#pragma unroll
    for (int j = 0; j < 4; ++j) acc[i][j] = (f32x4){0.f, 0.f, 0.f, 0.f};

  const int srow = tid >> 3;
  const int scol = ((tid & 7) ^ (srow & 7)) * 8;
  const unsigned short* gA = A + (size_t)(m0 + srow) * Kld + scol;
  const unsigned short* gB = Bt + (size_t)(n0 + srow) * Kld + scol;
  unsigned short* lA = sA + tid * 8;
  unsigned short* lB = sB + tid * 8;

  for (int k0 = 0; k0 < K; k0 += 64) {
    __syncthreads();
#pragma unroll
    for (int st = 0; st < 4; ++st) {
      async_load16(gA + (size_t)(st * 32) * Kld + k0, lA + st * 2048);
      async_load16(gB + (size_t)(st * 32) * Kld + k0, lB + st * 2048);
    }
    __syncthreads();

#pragma unroll
    for (int ks = 0; ks < 2; ++ks) {
      short8 af[4], bfr[4];
#pragma unroll
      for (int t = 0; t < 4; ++t) {
        const int cg = ((ks * 4 + quad) ^ swzb) * 8;
        af[t] = *(const short8*)(sA + (wm + t * 16 + l15) * 64 + cg);
        bfr[t] = *(const short8*)(sB + (wn + t * 16 + l15) * 64 + cg);
      }
#pragma unroll
      for (int mt = 0; mt < 4; ++mt)
#pragma unroll
        for (int nt = 0; nt < 4; ++nt)
          acc[mt][nt] = __builtin_amdgcn_mfma_f32_16x16x32_bf16(
              af[mt], bfr[nt], acc[mt][nt], 0, 0, 0);
    }
  }

  if (EPI == EPI_QKV && n0 >= 2048) {
    // ---- V block: transpose 128x128 tile via LDS -> Vt[bh][d][s] ----
    __syncthreads();
#pragma unroll
    for (int nt = 0; nt < 4; ++nt) {
      const int col = n0 + wn + nt * 16 + l15;
      const float bv = bias[col];
#pragma unroll
      for (int mt = 0; mt < 4; ++mt)
#pragma unroll
        for (int r = 0; r < 4; ++r)
          smem[(wn + nt * 16 + l15) * 136 + wm + mt * 16 + quad * 4 + r] =
              f2bf(acc[mt][nt][r] + bv);
    }
    __syncthreads();
    const int vc0 = n0 - 2048;
    const int bb = m0 >> 10;
    const int s0 = m0 & 1023;
#pragma unroll
    for (int i = 0; i < 8; ++i) {
      const int c = i * 16 + (tid >> 4);
      const int tc = tid & 15;
      const short8 val = *(const short8*)(smem + c * 136 + tc * 8);
      const int ch = vc0 + c;
      const int hh = ch >> 6, dd = ch & 63;
      *(short8*)(Vt + ((size_t)(bb * 16 + hh) * HD_ + dd) * S_ + s0 + tc * 8) =
          val;
    }
    return;
  }

#pragma unroll
  for (int nt = 0; nt < 4; ++nt) {
    const int col = n0 + wn + nt * 16 + l15;
    const float bv = bias[col];
    const float scl = (EPI == EPI_QKV && col < 1024) ? QSCALE : 1.0f;
#pragma unroll
    for (int mt = 0; mt < 4; ++mt) {
#pragma unroll
      for (int r = 0; r < 4; ++r) {
        const int row = m0 + wm + mt * 16 + quad * 4 + r;
        float v = acc[mt][nt][r] + bv;
        if (EPI == EPI_RELU_BF16) {
          ((unsigned short*)Cp)[(size_t)row * N + col] = f2bf(fmaxf(v, 0.f));
        } else {  // EPI_QKV Q/K
          ((unsigned short*)Cp)[(size_t)row * N + col] = f2bf(v * scl);
        }
      }
    }
  }
}

// ---------------------------------------------------------------------------
// FFN2 with intra-block split-K: 512 threads = 2 K-halves x 4 waves.
// A = hb [4096,2048] bf16, Bt = w2b [1024,2048] bf16, out fp32 [4096,1024].
// Halves stage into separate 32 KB LDS regions; combine via LDS at the end.
// ---------------------------------------------------------------------------
__global__ __launch_bounds__(512, 1) void gemm_ffn2(
    const unsigned short* __restrict__ A, const unsigned short* __restrict__ Bt,
    const float* __restrict__ bias, float* __restrict__ out) {
  __shared__ __align__(16) unsigned short smem[4 * 128 * 64];  // 64 KB
  const int tid512 = threadIdx.x;
  const int half = tid512 >> 8;   // K-half
  const int tid = tid512 & 255;
  unsigned short* sA = smem + half * 2 * 128 * 64;
  unsigned short* sB = sA + 128 * 64;

  const int lane = tid & 63;
  const int wave = tid >> 6;  // wave-in-half 0..3
  const int quad = lane >> 4;
  const int l15 = lane & 15;
  const int swzb = l15 & 7;
  const int m0 = blockIdx.y * 128;
  const int n0 = blockIdx.x * 128;
  const int wm = (wave >> 1) * 64;
  const int wn = (wave & 1) * 64;
  const int kz = half * 1024;

  f32x4 acc[4][4];
#pragma unroll
  for (int i = 0; i < 4; ++i)
#pragma unroll
    for (int j = 0; j < 4; ++j) acc[i][j] = (f32x4){0.f, 0.f, 0.f, 0.f};

  const int srow = tid >> 3;
  const int scol = ((tid & 7) ^ (srow & 7)) * 8;
  const unsigned short* gA = A + (size_t)(m0 + srow) * 2048 + kz + scol;
  const unsigned short* gB = Bt + (size_t)(n0 + srow) * 2048 + kz + scol;
  unsigned short* lA = sA + tid * 8;
  unsigned short* lB = sB + tid * 8;

  for (int k0 = 0; k0 < 1024; k0 += 64) {
    __syncthreads();
#pragma unroll
    for (int st = 0; st < 4; ++st) {
      async_load16(gA + (size_t)(st * 32) * 2048 + k0, lA + st * 2048);
      async_load16(gB + (size_t)(st * 32) * 2048 + k0, lB + st * 2048);
    }
    __syncthreads();

#pragma unroll
    for (int ks = 0; ks < 2; ++ks) {
      short8 af[4], bfr[4];
#pragma unroll
      for (int t = 0; t < 4; ++t) {
        const int cg = ((ks * 4 + quad) ^ swzb) * 8;
        af[t] = *(const short8*)(sA + (wm + t * 16 + l15) * 64 + cg);
        bfr[t] = *(const short8*)(sB + (wn + t * 16 + l15) * 64 + cg);
      }
#pragma unroll
      for (int mt = 0; mt < 4; ++mt)
#pragma unroll
        for (int nt = 0; nt < 4; ++nt)
          acc[mt][nt] = __builtin_amdgcn_mfma_f32_16x16x32_bf16(
              af[mt], bfr[nt], acc[mt][nt], 0, 0, 0);
    }
  }

  // ---- combine halves via LDS (reuse the 64 KB as fp32 16K) ----
  __syncthreads();  // all ds_reads of staging done
  float* fbuf = (float*)smem;  // [4 waves][64 rows][64 cols]
  if (half == 1) {
#pragma unroll
    for (int nt = 0; nt < 4; ++nt)
#pragma unroll
      for (int mt = 0; mt < 4; ++mt)
#pragma unroll
        for (int r = 0; r < 4; ++r)
          fbuf[wave * 4096 + (mt * 16 + quad * 4 + r) * 64 + nt * 16 + l15] =
              acc[mt][nt][r];
  }
  __syncthreads();
  if (half == 0) {
#pragma unroll
    for (int nt = 0; nt < 4; ++nt) {
      const int col = n0 + wn + nt * 16 + l15;
      const float bv = bias[col];
#pragma unroll
      for (int mt = 0; mt < 4; ++mt)
#pragma unroll
        for (int r = 0; r < 4; ++r) {
          const int row = m0 + wm + mt * 16 + quad * 4 + r;
          const float v =
              acc[mt][nt][r] +
              fbuf[wave * 4096 + (mt * 16 + quad * 4 + r) * 64 + nt * 16 + l15] +
              bv;
          out[(size_t)row * DM_ + col] = v;
        }
    }
  }
}

// ---------------------------------------------------------------------------
// Flash attention (R7 structure): grid (bh=64, qtile=8), 4 waves x 32 q-rows;
// P buffer 32x136/wave, PV for both subtiles off one V-frag read; K from
// token-major Cqkv, V from Vt; fixed-base exp2 softmax; deferred row-sum.
// ---------------------------------------------------------------------------
__global__ __launch_bounds__(256, 2) void flash_attn(
    const unsigned short* __restrict__ Cqkv, const unsigned short* __restrict__ Vt,
    const unsigned long long* __restrict__ mbits,
    const unsigned int* __restrict__ mrowflag,
    unsigned short* __restrict__ ctx) {
  __shared__ unsigned short sK[128 * 64];
  __shared__ unsigned short sV[64 * 128];
  __shared__ unsigned short spb[4][32 * 136];

  const int tid = threadIdx.x;
  const int wave = tid >> 6;
  const int lane = tid & 63;
  const int quad = lane >> 4;
  const int l15 = lane & 15;
  const int bh = blockIdx.x;
  const int b = bh >> 4;
  const int h = bh & 15;
  const int qbase = blockIdx.y * 128 + wave * 32;

  const unsigned short* Qb = Cqkv + (size_t)(b * S_) * 3072 + h * HD_;
  const unsigned short* Kb = Cqkv + (size_t)(b * S_) * 3072 + DM_ + h * HD_;
  const unsigned short* Vb = Vt + (size_t)bh * HD_ * S_;
  unsigned short* pbuf = spb[wave];

  bool mask_all_ones;
  {
    unsigned int f = mrowflag[b * S_ + qbase + (lane & 31)];
    mask_all_ones = (__ballot(f != 0) == ~0ull);
  }

  short8 qf[2][2];
#pragma unroll
  for (int u = 0; u < 2; ++u)
#pragma unroll
    for (int ks = 0; ks < 2; ++ks)
      qf[u][ks] = *(const short8*)(Qb + (size_t)(qbase + u * 16 + l15) * 3072 +
                                   ks * 32 + quad * 8);

  f32x4 o[2][4];
#pragma unroll
  for (int u = 0; u < 2; ++u)
#pragma unroll
    for (int i = 0; i < 4; ++i) o[u][i] = (f32x4){0.f, 0.f, 0.f, 0.f};
  float lsum[2][4] = {{0.f, 0.f, 0.f, 0.f}, {0.f, 0.f, 0.f, 0.f}};

  for (int kt = 0; kt < S_ / 128; ++kt) {
    const int kbase = kt * 128;

    __syncthreads();
#pragma unroll
    for (int st = 0; st < 4; ++st) {
      const int j = st * 256 + tid;
      const int r = j >> 3, c = j & 7;
      async_load16(Kb + (size_t)(kbase + r) * 3072 + ((c ^ (r & 7)) * 8),
                   sK + j * 8);
    }
#pragma unroll
    for (int st = 0; st < 4; ++st) {
      const int j = st * 256 + tid;
      const int d = j >> 4, c = j & 15;
      async_load16(Vb + (size_t)d * S_ + kbase + ((c ^ (d & 15)) * 8),
                   sV + j * 8);
    }
    __syncthreads();

    f32x4 s[2][8];
#pragma unroll
    for (int u = 0; u < 2; ++u)
#pragma unroll
      for (int i = 0; i < 8; ++i) s[u][i] = (f32x4){0.f, 0.f, 0.f, 0.f};
#pragma unroll
    for (int ks = 0; ks < 2; ++ks) {
      const int cg = ks * 4 + quad;
#pragma unroll
      for (int nt = 0; nt < 8; ++nt) {
        const int row = nt * 16 + l15;
        const short8 kf =
            *(const short8*)(sK + row * 64 + ((cg ^ (row & 7)) * 8));
        s[0][nt] = __builtin_amdgcn_mfma_f32_16x16x32_bf16(qf[0][ks], kf,
                                                           s[0][nt], 0, 0, 0);
        s[1][nt] = __builtin_amdgcn_mfma_f32_16x16x32_bf16(qf[1][ks], kf,
                                                           s[1][nt], 0, 0, 0);
      }
    }

    if (!mask_all_ones) {
#pragma unroll
      for (int u = 0; u < 2; ++u)
#pragma unroll
        for (int r = 0; r < 4; ++r) {
          const int q = qbase + u * 16 + quad * 4 + r;
          const unsigned long long* wp =
              mbits + ((size_t)(b * S_ + q)) * 16 + kt * 2;
          const unsigned long long w0 = wp[0], w1 = wp[1];
#pragma unroll
          for (int nt = 0; nt < 8; ++nt) {
            const unsigned long long w = (nt < 4) ? w0 : w1;
            const int bit = (nt * 16 + l15) & 63;
            if (!((w >> bit) & 1)) s[u][nt][r] = -1.0e8f;
          }
        }
    }

#pragma unroll
    for (int u = 0; u < 2; ++u)
#pragma unroll
      for (int nt = 0; nt < 8; ++nt)
#pragma unroll
        for (int r = 0; r < 4; ++r) {
          const float p = __builtin_amdgcn_exp2f(s[u][nt][r]);
          lsum[u][r] += p;
          pbuf[(u * 16 + quad * 4 + r) * 136 + nt * 16 + l15] = f2bf(p);
        }

#pragma unroll
    for (int ks2 = 0; ks2 < 4; ++ks2) {
      const short8 pf0 =
          *(const short8*)(pbuf + l15 * 136 + ks2 * 32 + quad * 8);
      const short8 pf1 =
          *(const short8*)(pbuf + (16 + l15) * 136 + ks2 * 32 + quad * 8);
      const int cg = ks2 * 4 + quad;
#pragma unroll
      for (int nt = 0; nt < 4; ++nt) {
        const int d = nt * 16 + l15;
        const short8 vf =
            *(const short8*)(sV + d * 128 + ((cg ^ (d & 15)) * 8));
        o[0][nt] = __builtin_amdgcn_mfma_f32_16x16x32_bf16(pf0, vf, o[0][nt], 0, 0, 0);
        o[1][nt] = __builtin_amdgcn_mfma_f32_16x16x32_bf16(pf1, vf, o[1][nt], 0, 0, 0);
      }
    }
  }

#pragma unroll
  for (int u = 0; u < 2; ++u)
#pragma unroll
    for (int r = 0; r < 4; ++r) {
      float lr = lsum[u][r];
      lr += __shfl_xor(lr, 1);
      lr += __shfl_xor(lr, 2);
      lr += __shfl_xor(lr, 4);
      lr += __shfl_xor(lr, 8);
      const float inv = 1.0f / lr;
#pragma unroll
      for (int nt = 0; nt < 4; ++nt)
        pbuf[(u * 16 + quad * 4 + r) * 68 + nt * 16 + l15] =
            f2bf(o[u][nt][r] * inv);
    }
#pragma unroll
  for (int i = 0; i < 4; ++i) {
    const int j = i * 64 + lane;
    const int r = j >> 3, c = j & 7;
    const short8 val = *(const short8*)(pbuf + r * 68 + c * 8);
    *(short8*)(ctx + ((size_t)b * S_ + qbase + r) * DM_ + h * HD_ + c * 8) = val;
  }
}

// ---------------------------------------------------------------------------
// launch
// ---------------------------------------------------------------------------
extern "C" void kernel_launch(void* const* d_in, const int* in_sizes, int n_in,
                              void* d_out, int out_size, void* d_ws,
                              size_t ws_size, hipStream_t stream) {
  const float* x = (const float*)d_in[0];
  const float* Wq = (const float*)d_in[1];
  const float* bq = (const float*)d_in[2];
  const float* Wk = (const float*)d_in[3];
  const float* bk = (const float*)d_in[4];
  const float* Wv = (const float*)d_in[5];
  const float* bv = (const float*)d_in[6];
  const float* W1 = (const float*)d_in[7];
  const float* b1 = (const float*)d_in[8];
  const float* W2 = (const float*)d_in[9];
  const float* b2 = (const float*)d_in[10];
  const int* mask = (const int*)d_in[11];
  float* out = (float*)d_out;

  char* ws = (char*)d_ws;
  unsigned short* xb   = (unsigned short*)(ws + 0);          //  8 MB
  unsigned short* wqkv = (unsigned short*)(ws + 8388608);    //  6 MB
  unsigned short* w1b  = (unsigned short*)(ws + 14680064);   //  4 MB
  unsigned short* w2b  = (unsigned short*)(ws + 18874368);   //  4 MB
  unsigned short* Cqkv = (unsigned short*)(ws + 23068672);   // 24 MB
  unsigned short* ctxb = (unsigned short*)(ws + 48234496);   //  8 MB
  unsigned short* hb   = (unsigned short*)(ws + 56623104);   // 16 MB
  unsigned short* Vt   = (unsigned short*)(ws + 56623104);   //  8 MB (hb reuse)
  unsigned long long* mbits = (unsigned long long*)(ws + 73400320);  // 512 KB
  unsigned int* mrowflag    = (unsigned int*)(ws + 73924608);        //  16 KB
  float* cb                 = (float*)(ws + 73940992);               //  12 KB

  PrepArgs pa;
  pa.src[0] = x;  pa.dst[0] = xb;               pa.n4[0] = (B_ * S_ * DM_) / 4;
  pa.src[1] = Wq; pa.dst[1] = wqkv;             pa.n4[1] = (DM_ * DM_) / 4;
  pa.src[2] = Wk; pa.dst[2] = wqkv + DM_ * DM_; pa.n4[2] = (DM_ * DM_) / 4;
  pa.src[3] = Wv; pa.dst[3] = wqkv + 2 * DM_ * DM_; pa.n4[3] = (DM_ * DM_) / 4;
  pa.src[4] = W1; pa.dst[4] = w1b;              pa.n4[4] = (2 * DM_ * DM_) / 4;
  pa.src[5] = W2; pa.dst[5] = w2b;              pa.n4[5] = (2 * DM_ * DM_) / 4;
  pa.mask = mask; pa.bits = mbits; pa.rowflag = mrowflag;
  pa.bq = bq; pa.bk = bk; pa.bv = bv; pa.cb = cb;
  prep_kernel<<<dim3(1024, 8), 256, 0, stream>>>(pa);

  const int M = B_ * S_;  // 4096
  gemm_bt<EPI_QKV><<<dim3(3 * DM_ / 128, M / 128), 256, 0, stream>>>(
      xb, wqkv, cb, Cqkv, Vt, M, 3 * DM_, DM_, DM_);

  flash_attn<<<dim3(B_ * H_, S_ / 128), 256, 0, stream>>>(
      Cqkv, Vt, mbits, mrowflag, ctxb);

  gemm_bt<EPI_RELU_BF16><<<dim3((2 * DM_) / 128, M / 128), 256, 0, stream>>>(
      ctxb, w1b, b1, hb, nullptr, M, 2 * DM_, DM_, DM_);

  gemm_ffn2<<<dim3(DM_ / 128, M / 128), 512, 0, stream>>>(hb, w2b, b2, out);
}